// Round 1
// baseline (158.423 us; speedup 1.0000x reference)
//
#include <hip/hip_runtime.h>
#include <hip/hip_bf16.h>

// Problem constants (fixed by reference)
#define BATCH 2
#define NPTS  8192
#define BN    (BATCH * NPTS)   // 16384
#define KNN   16
#define HEADS 4
#define HD    128              // HEADS*32
#define CIN   64
#define COUT  128
#define WCOLS 384              // [WqA1 | WkA1 | Wv] columns

using short8  = __attribute__((ext_vector_type(8))) short;
using float4v = __attribute__((ext_vector_type(4))) float;

static __device__ __forceinline__ unsigned short f2bf(float x) {
    unsigned u = __float_as_uint(x);
    u += 0x7fffu + ((u >> 16) & 1u);          // round-to-nearest-even
    return (unsigned short)(u >> 16);
}
static __device__ __forceinline__ float bf_lo(unsigned u) { return __uint_as_float(u << 16); }
static __device__ __forceinline__ float bf_hi(unsigned u) { return __uint_as_float(u & 0xffff0000u); }
static __device__ __forceinline__ unsigned pack2(float a, float b) {
    return (unsigned)f2bf(a) | ((unsigned)f2bf(b) << 16);
}

// DPP row ops (row = 16 lanes). row_ror:n ctrl = 0x120+n.
template <int CTRL>
static __device__ __forceinline__ float dpp_mov(float x) {
    return __int_as_float(
        __builtin_amdgcn_update_dpp(0, __float_as_int(x), CTRL, 0xf, 0xf, false));
}
static __device__ __forceinline__ float ror_sum16(float x) {
    x += dpp_mov<0x128>(x);
    x += dpp_mov<0x124>(x);
    x += dpp_mov<0x122>(x);
    x += dpp_mov<0x121>(x);
    return x;
}
static __device__ __forceinline__ float ror_max16(float x) {
    x = fmaxf(x, dpp_mov<0x128>(x));
    x = fmaxf(x, dpp_mov<0x124>(x));
    x = fmaxf(x, dpp_mov<0x122>(x));
    x = fmaxf(x, dpp_mov<0x121>(x));
    return x;
}

// ---------------------------------------------------------------------------
// Kernel P: fold weights into MFMA-ready transposed bf16 operands.
//   WcatT[n][k] bf16, n in [0,384), k in [0,64):
//        n<128: (Wq@A1)[k][n] ; n<256: (Wk@A1)[k][n-128] ; else Wv[k][n-256]
//   WoutT[n][k] bf16 = Wout[k][n]          (n,k in [0,128))
//   P2A1[3][128] fp32 = P2@A1
//   cvec[128] fp32 = b1 + bp2@A1
// ---------------------------------------------------------------------------
__global__ void prep_kernel(const float* __restrict__ Wk,
                            const float* __restrict__ Wv,
                            const float* __restrict__ Wq,
                            const float* __restrict__ A1,
                            const float* __restrict__ b1,
                            const float* __restrict__ P2,
                            const float* __restrict__ bp2,
                            const float* __restrict__ Wout,
                            unsigned short* __restrict__ WcatT,
                            unsigned short* __restrict__ WoutT,
                            float* __restrict__ P2A1,
                            float* __restrict__ cvec) {
    int t = blockIdx.x * blockDim.x + threadIdx.x;
    if (t < WCOLS * CIN) {                     // WcatT: u = n*64 + kk
        int n = t >> 6, kk = t & 63;
        float val;
        if (n < 2 * HD) {
            const float* w = (n < HD ? Wq : Wk) + kk * HD;
            int jj = n & (HD - 1);
            float acc = 0.f;
            #pragma unroll 4
            for (int m = 0; m < HD; m += 4) {
                float4 wr = *(const float4*)(w + m);
                acc += wr.x * A1[(m+0)*HD + jj] + wr.y * A1[(m+1)*HD + jj]
                     + wr.z * A1[(m+2)*HD + jj] + wr.w * A1[(m+3)*HD + jj];
            }
            val = acc;
        } else {
            val = Wv[kk * HD + (n - 2 * HD)];
        }
        WcatT[t] = f2bf(val);
    } else if (t < WCOLS * CIN + COUT * HD) {  // WoutT: u = n*128 + kk
        int u = t - WCOLS * CIN;
        int n = u >> 7, kk = u & 127;
        WoutT[u] = f2bf(Wout[kk * COUT + n]);
    } else if (t < WCOLS * CIN + COUT * HD + 3 * HD) {
        int u = t - (WCOLS * CIN + COUT * HD);
        int r = u / HD, j = u % HD;
        const float* w = P2 + r * HD;
        float acc = 0.f;
        #pragma unroll 4
        for (int m = 0; m < HD; m += 4) {
            float4 wr = *(const float4*)(w + m);
            acc += wr.x * A1[(m+0)*HD + j] + wr.y * A1[(m+1)*HD + j]
                 + wr.z * A1[(m+2)*HD + j] + wr.w * A1[(m+3)*HD + j];
        }
        P2A1[u] = acc;
    } else if (t < WCOLS * CIN + COUT * HD + 3 * HD + HD) {
        int j = t - (WCOLS * CIN + COUT * HD + 3 * HD);
        float acc = b1[j];
        #pragma unroll 4
        for (int m = 0; m < HD; m += 4) {
            float4 wr = *(const float4*)(bp2 + m);
            acc += wr.x * A1[(m+0)*HD + j] + wr.y * A1[(m+1)*HD + j]
                 + wr.z * A1[(m+2)*HD + j] + wr.w * A1[(m+3)*HD + j];
        }
        cvec[j] = acc;
    }
}

// ---------------------------------------------------------------------------
// Kernel A (MFMA): QKVb[16384][384] bf16 = bf16(F) @ Wcat (+cvec on n<128).
// n<128: pre-ReLU z query part; 128..255: K; 256..383: V.
// Block: 64 rows, 4 waves (wave = 16 rows), K=64 (2 mfma/nt), nt=24.
// A-frag: lane(m=l&15, k=quad*8..+7); B stored transposed [n][k] likewise.
// LDS stride 88 elems (176 B, 16B-multiple, 2-way bank alias on frag reads).
// ---------------------------------------------------------------------------
#define AK 88
__global__ __launch_bounds__(256) void qkv_kernel(const float* __restrict__ F,
                                                  const unsigned short* __restrict__ WcatT,
                                                  const float* __restrict__ cvec,
                                                  unsigned short* __restrict__ QKVb) {
    __shared__ unsigned short Af[64 * AK];     // 11.3 KB
    __shared__ unsigned short Bf[WCOLS * AK];  // 67.6 KB
    int p0 = blockIdx.x * 64;
    int t = threadIdx.x;

    // stage A: 64x64 fp32 -> bf16
    #pragma unroll
    for (int i = 0; i < 4; ++i) {
        int v = t + i * 256;
        int row = v >> 4, c4 = (v & 15) * 4;
        float4 fa = *(const float4*)(F + (p0 + row) * CIN + c4);
        uint2 u = make_uint2(pack2(fa.x, fa.y), pack2(fa.z, fa.w));
        *(uint2*)(&Af[row * AK + c4]) = u;
    }
    // stage B: 384x64 bf16
    #pragma unroll
    for (int i = 0; i < 12; ++i) {
        int v = t + i * 256;                   // uint4 index: n = v>>3, j16 = v&7
        int n = v >> 3, j16 = v & 7;
        *(uint4*)(&Bf[n * AK + j16 * 8]) = ((const uint4*)WcatT)[v];
    }
    __syncthreads();

    int w = t >> 6, l = t & 63;
    int ml = l & 15, quad = l >> 4;
    int m0 = w * 16;

    short8 a0 = *(const short8*)(&Af[(m0 + ml) * AK + quad * 8]);
    short8 a1 = *(const short8*)(&Af[(m0 + ml) * AK + 32 + quad * 8]);

    #pragma unroll
    for (int nt = 0; nt < 24; ++nt) {
        short8 b0 = *(const short8*)(&Bf[(nt * 16 + ml) * AK + quad * 8]);
        short8 b1 = *(const short8*)(&Bf[(nt * 16 + ml) * AK + 32 + quad * 8]);
        float4v acc = {0.f, 0.f, 0.f, 0.f};
        acc = __builtin_amdgcn_mfma_f32_16x16x32_bf16(a0, b0, acc, 0, 0, 0);
        acc = __builtin_amdgcn_mfma_f32_16x16x32_bf16(a1, b1, acc, 0, 0, 0);
        int n = nt * 16 + ml;
        float cadd = (n < HD) ? cvec[n] : 0.f;
        #pragma unroll
        for (int r = 0; r < 4; ++r) {
            int row = p0 + m0 + quad * 4 + r;
            QKVb[row * WCOLS + n] = f2bf(acc[r] + cadd);
        }
    }
}

// ---------------------------------------------------------------------------
// Kernel B: per-point attention (DPP, unchanged structure from R4).
// Reads bf16 QKVb: q at [p][c0], K at [q][128+c0], V at [q][256+c0].
// Writes FUSEDb bf16.
// ---------------------------------------------------------------------------
__global__ __launch_bounds__(256) void attn_kernel(
        const float* __restrict__ xyzs, const int* __restrict__ kg,
        const unsigned short* __restrict__ QKVb,
        const float* __restrict__ P1, const float* __restrict__ bp1,
        const float* __restrict__ P2, const float* __restrict__ bp2,
        const float* __restrict__ P2A1,
        const float* __restrict__ A2, const float* __restrict__ b2,
        unsigned short* __restrict__ FUSEDb) {
    int p = blockIdx.x;
    int b = p >> 13;              // p / NPTS
    int t = threadIdx.x;
    int g = t >> 4, k = t & 15, c0 = g * 8;
    int w = t >> 6;               // wave = head of this thread's channels
    int lane = t & 63;

    __shared__ float4 A2s[HD];
    __shared__ float4 lgp[4][16];
    __shared__ float4 hs16[16];
    __shared__ float  ats[64];
    __shared__ float4 hbf[4];

    if (t < HD) A2s[t] = *(const float4*)(A2 + t * 4);

    int idx = kg[p * KNN + k];
    int q = b * NPTS + idx;

    float r0 = xyzs[p*3+0] - xyzs[q*3+0];
    float r1 = xyzs[p*3+1] - xyzs[q*3+1];
    float r2 = xyzs[p*3+2] - xyzs[q*3+2];
    float h0 = fmaxf(r0*P1[0] + r1*P1[3] + r2*P1[6] + bp1[0], 0.f);
    float h1 = fmaxf(r0*P1[1] + r1*P1[4] + r2*P1[7] + bp1[1], 0.f);
    float h2 = fmaxf(r0*P1[2] + r1*P1[5] + r2*P1[8] + bp1[2], 0.f);
    if (g == 0) hs16[k] = make_float4(h0, h1, h2, 0.f);

    uint4 qu = *(const uint4*)(QKVb + p * WCOLS + c0);
    uint4 ku = *(const uint4*)(QKVb + q * WCOLS + HD + c0);
    uint4 vu = *(const uint4*)(QKVb + q * WCOLS + 2 * HD + c0);

    float qz[8] = { bf_lo(qu.x), bf_hi(qu.x), bf_lo(qu.y), bf_hi(qu.y),
                    bf_lo(qu.z), bf_hi(qu.z), bf_lo(qu.w), bf_hi(qu.w) };
    float kr[8] = { bf_lo(ku.x), bf_hi(ku.x), bf_lo(ku.y), bf_hi(ku.y),
                    bf_lo(ku.z), bf_hi(ku.z), bf_lo(ku.w), bf_hi(ku.w) };

    float wa0[8], wa1[8], wa2[8];
    *(float4*)(wa0)     = *(const float4*)(P2A1 + 0*HD + c0);
    *(float4*)(wa0 + 4) = *(const float4*)(P2A1 + 0*HD + c0 + 4);
    *(float4*)(wa1)     = *(const float4*)(P2A1 + 1*HD + c0);
    *(float4*)(wa1 + 4) = *(const float4*)(P2A1 + 1*HD + c0 + 4);
    *(float4*)(wa2)     = *(const float4*)(P2A1 + 2*HD + c0);
    *(float4*)(wa2 + 4) = *(const float4*)(P2A1 + 2*HD + c0 + 4);

    __syncthreads();   // A2s / hs16 visible

    float pl0 = 0.f, pl1 = 0.f, pl2 = 0.f, pl3 = 0.f;
    #pragma unroll
    for (int j = 0; j < 8; ++j) {
        float z = fmaxf(qz[j] - kr[j] + h0*wa0[j] + h1*wa1[j] + h2*wa2[j], 0.f);
        float4 ar = A2s[c0 + j];
        pl0 += z * ar.x; pl1 += z * ar.y; pl2 += z * ar.z; pl3 += z * ar.w;
    }
    pl0 += __shfl_xor(pl0, 16, 64); pl0 += __shfl_xor(pl0, 32, 64);
    pl1 += __shfl_xor(pl1, 16, 64); pl1 += __shfl_xor(pl1, 32, 64);
    pl2 += __shfl_xor(pl2, 16, 64); pl2 += __shfl_xor(pl2, 32, 64);
    pl3 += __shfl_xor(pl3, 16, 64); pl3 += __shfl_xor(pl3, 32, 64);
    if (lane < 16) lgp[w][lane] = make_float4(pl0, pl1, pl2, pl3);
    __syncthreads();

    if (t < 64) {
        int hh = t >> 4, kk = t & 15;
        const float* lp = (const float*)lgp;
        float lgt = b2[hh] + lp[0*64 + kk*4 + hh] + lp[1*64 + kk*4 + hh]
                           + lp[2*64 + kk*4 + hh] + lp[3*64 + kk*4 + hh];
        float m = ror_max16(lgt);
        float e = __expf(lgt - m);
        float s = ror_sum16(e);
        float a = e / s;
        ats[t] = a;
        float4 hv = hs16[kk];
        float hb0 = ror_sum16(a * hv.x);
        float hb1 = ror_sum16(a * hv.y);
        float hb2 = ror_sum16(a * hv.z);
        if (kk == 0) hbf[hh] = make_float4(hb0, hb1, hb2, 0.f);
    }
    __syncthreads();

    float a = ats[w * 16 + k];
    float vr[8] = { bf_lo(vu.x), bf_hi(vu.x), bf_lo(vu.y), bf_hi(vu.y),
                    bf_lo(vu.z), bf_hi(vu.z), bf_lo(vu.w), bf_hi(vu.w) };
    float wv[8];
    #pragma unroll
    for (int j = 0; j < 8; ++j) wv[j] = ror_sum16(a * vr[j]);

    if (k == 0) {
        float4 hb = hbf[w];
        float q0[8], q1[8], q2[8], bpv[8];
        *(float4*)(q0)     = *(const float4*)(P2 + 0*HD + c0);
        *(float4*)(q0 + 4) = *(const float4*)(P2 + 0*HD + c0 + 4);
        *(float4*)(q1)     = *(const float4*)(P2 + 1*HD + c0);
        *(float4*)(q1 + 4) = *(const float4*)(P2 + 1*HD + c0 + 4);
        *(float4*)(q2)     = *(const float4*)(P2 + 2*HD + c0);
        *(float4*)(q2 + 4) = *(const float4*)(P2 + 2*HD + c0 + 4);
        *(float4*)(bpv)     = *(const float4*)(bp2 + c0);
        *(float4*)(bpv + 4) = *(const float4*)(bp2 + c0 + 4);
        float f[8];
        #pragma unroll
        for (int j = 0; j < 8; ++j)
            f[j] = wv[j] + hb.x*q0[j] + hb.y*q1[j] + hb.z*q2[j] + bpv[j];
        uint4 fu;
        fu.x = pack2(f[0], f[1]); fu.y = pack2(f[2], f[3]);
        fu.z = pack2(f[4], f[5]); fu.w = pack2(f[6], f[7]);
        *(uint4*)(FUSEDb + p * HD + c0) = fu;
    }
}

// ---------------------------------------------------------------------------
// Kernel C (MFMA): out[16384][128] = FUSEDb @ Wout + bout (fp32 out).
// Block: 64 rows, 4 waves, K=128 (4 mfma/nt), nt=8.
// LDS stride 144 elems (288 B) -> conflict-free frag reads.
// ---------------------------------------------------------------------------
#define OK2 144
__global__ __launch_bounds__(256) void out_kernel(const unsigned short* __restrict__ FUSEDb,
                                                  const unsigned short* __restrict__ WoutT,
                                                  const float* __restrict__ bout,
                                                  float* __restrict__ out) {
    __shared__ unsigned short Af[64 * OK2];    // 18.4 KB
    __shared__ unsigned short Bf[HD * OK2];    // 36.9 KB
    int p0 = blockIdx.x * 64;
    int t = threadIdx.x;

    #pragma unroll
    for (int i = 0; i < 4; ++i) {              // stage A: 64 x 128 bf16
        int v = t + i * 256;
        int row = v >> 4, j16 = v & 15;
        *(uint4*)(&Af[row * OK2 + j16 * 8]) = ((const uint4*)FUSEDb)[(p0 + row) * 16 + j16];
    }
    #pragma unroll
    for (int i = 0; i < 8; ++i) {              // stage B: 128 x 128 bf16
        int v = t + i * 256;
        int n = v >> 4, j16 = v & 15;
        *(uint4*)(&Bf[n * OK2 + j16 * 8]) = ((const uint4*)WoutT)[v];
    }
    __syncthreads();

    int w = t >> 6, l = t & 63;
    int ml = l & 15, quad = l >> 4;
    int m0 = w * 16;

    short8 af[4];
    #pragma unroll
    for (int ks = 0; ks < 4; ++ks)
        af[ks] = *(const short8*)(&Af[(m0 + ml) * OK2 + ks * 32 + quad * 8]);

    #pragma unroll
    for (int nt = 0; nt < 8; ++nt) {
        float4v acc = {0.f, 0.f, 0.f, 0.f};
        #pragma unroll
        for (int ks = 0; ks < 4; ++ks) {
            short8 bf = *(const short8*)(&Bf[(nt * 16 + ml) * OK2 + ks * 32 + quad * 8]);
            acc = __builtin_amdgcn_mfma_f32_16x16x32_bf16(af[ks], bf, acc, 0, 0, 0);
        }
        int n = nt * 16 + ml;
        float bo = bout[n];
        #pragma unroll
        for (int r = 0; r < 4; ++r) {
            int row = p0 + m0 + quad * 4 + r;
            out[row * COUT + n] = acc[r] + bo;
        }
    }
}

// ---------------------------------------------------------------------------
extern "C" void kernel_launch(void* const* d_in, const int* in_sizes, int n_in,
                              void* d_out, int out_size, void* d_ws, size_t ws_size,
                              hipStream_t stream) {
    const float* xyzs = (const float*)d_in[0];
    const float* feat = (const float*)d_in[1];
    const int*   kg   = (const int*)  d_in[2];
    const float* Wk   = (const float*)d_in[3];
    const float* Wv   = (const float*)d_in[4];
    const float* Wq   = (const float*)d_in[5];
    const float* A1   = (const float*)d_in[6];
    const float* b1   = (const float*)d_in[7];
    const float* A2   = (const float*)d_in[8];
    const float* b2   = (const float*)d_in[9];
    const float* P1   = (const float*)d_in[10];
    const float* bp1  = (const float*)d_in[11];
    const float* P2   = (const float*)d_in[12];
    const float* bp2  = (const float*)d_in[13];
    const float* Wout = (const float*)d_in[14];
    const float* bout = (const float*)d_in[15];
    float* out = (float*)d_out;

    float* ws = (float*)d_ws;
    float* cvec = ws;                               // 128 fp32
    float* P2A1 = ws + 128;                         // 384 fp32  (total 512 fp32 = 2048 B)
    unsigned short* QKVb  = (unsigned short*)(ws + 512);         // BN*384 bf16 (12.6 MB)
    unsigned short* FUSEDb = QKVb + (size_t)BN * WCOLS;          // BN*128 bf16 (4 MB)
    unsigned short* WcatT = FUSEDb + (size_t)BN * HD;            // 384*64 bf16
    unsigned short* WoutT = WcatT + WCOLS * CIN;                 // 128*128 bf16

    int prep_elems = WCOLS*CIN + COUT*HD + 3*HD + HD;  // 41472
    prep_kernel<<<(prep_elems + 255) / 256, 256, 0, stream>>>(
        Wk, Wv, Wq, A1, b1, P2, bp2, Wout, WcatT, WoutT, P2A1, cvec);

    qkv_kernel<<<BN / 64, 256, 0, stream>>>(feat, WcatT, cvec, QKVb);

    attn_kernel<<<BN, 256, 0, stream>>>(
        xyzs, kg, QKVb, P1, bp1, P2, bp2, P2A1, A2, b2, FUSEDb);

    out_kernel<<<BN / 64, 256, 0, stream>>>(FUSEDb, WoutT, bout, out);
}

// Round 2
// 140.225 us; speedup vs baseline: 1.1298x; 1.1298x over previous
//
#include <hip/hip_runtime.h>
#include <hip/hip_bf16.h>

// Problem constants (fixed by reference)
#define BATCH 2
#define NPTS  8192
#define BN    (BATCH * NPTS)   // 16384
#define KNN   16
#define HEADS 4
#define HD    128              // HEADS*32
#define CIN   64
#define COUT  128
#define WCOLS 384              // [WqA1 | WkA1 | Wv] columns

using short8  = __attribute__((ext_vector_type(8))) short;
using float4v = __attribute__((ext_vector_type(4))) float;

static __device__ __forceinline__ unsigned short f2bf(float x) {
    unsigned u = __float_as_uint(x);
    u += 0x7fffu + ((u >> 16) & 1u);          // round-to-nearest-even
    return (unsigned short)(u >> 16);
}
static __device__ __forceinline__ float bf_lo(unsigned u) { return __uint_as_float(u << 16); }
static __device__ __forceinline__ float bf_hi(unsigned u) { return __uint_as_float(u & 0xffff0000u); }
static __device__ __forceinline__ unsigned pack2(float a, float b) {
    return (unsigned)f2bf(a) | ((unsigned)f2bf(b) << 16);
}
static __device__ __forceinline__ void unpack8(uint4 u, float* f) {
    f[0] = bf_lo(u.x); f[1] = bf_hi(u.x);
    f[2] = bf_lo(u.y); f[3] = bf_hi(u.y);
    f[4] = bf_lo(u.z); f[5] = bf_hi(u.z);
    f[6] = bf_lo(u.w); f[7] = bf_hi(u.w);
}

// DPP row ops (row = 16 lanes). row_ror:n ctrl = 0x120+n.
template <int CTRL>
static __device__ __forceinline__ float dpp_mov(float x) {
    return __int_as_float(
        __builtin_amdgcn_update_dpp(0, __float_as_int(x), CTRL, 0xf, 0xf, false));
}
static __device__ __forceinline__ float ror_sum16(float x) {
    x += dpp_mov<0x128>(x);
    x += dpp_mov<0x124>(x);
    x += dpp_mov<0x122>(x);
    x += dpp_mov<0x121>(x);
    return x;
}
static __device__ __forceinline__ float ror_max16(float x) {
    x = fmaxf(x, dpp_mov<0x128>(x));
    x = fmaxf(x, dpp_mov<0x124>(x));
    x = fmaxf(x, dpp_mov<0x122>(x));
    x = fmaxf(x, dpp_mov<0x121>(x));
    return x;
}

// ---------------------------------------------------------------------------
// Kernel P: fold weights into MFMA-ready transposed bf16 operands.
//   WcatT[n][k] bf16, n in [0,384), k in [0,64):
//        n<128: (Wq@A1)[k][n] ; n<256: (Wk@A1)[k][n-128] ; else Wv[k][n-256]
//   WoutT[n][k] bf16 = Wout[k][n]          (n,k in [0,128))
//   P2A1[3][128] fp32 = P2@A1
//   cvec[128] fp32 = b1 + bp2@A1
// ---------------------------------------------------------------------------
__global__ void prep_kernel(const float* __restrict__ Wk,
                            const float* __restrict__ Wv,
                            const float* __restrict__ Wq,
                            const float* __restrict__ A1,
                            const float* __restrict__ b1,
                            const float* __restrict__ P2,
                            const float* __restrict__ bp2,
                            const float* __restrict__ Wout,
                            unsigned short* __restrict__ WcatT,
                            unsigned short* __restrict__ WoutT,
                            float* __restrict__ P2A1,
                            float* __restrict__ cvec) {
    int t = blockIdx.x * blockDim.x + threadIdx.x;
    if (t < WCOLS * CIN) {                     // WcatT: u = n*64 + kk
        int n = t >> 6, kk = t & 63;
        float val;
        if (n < 2 * HD) {
            const float* w = (n < HD ? Wq : Wk) + kk * HD;
            int jj = n & (HD - 1);
            float acc = 0.f;
            #pragma unroll 4
            for (int m = 0; m < HD; m += 4) {
                float4 wr = *(const float4*)(w + m);
                acc += wr.x * A1[(m+0)*HD + jj] + wr.y * A1[(m+1)*HD + jj]
                     + wr.z * A1[(m+2)*HD + jj] + wr.w * A1[(m+3)*HD + jj];
            }
            val = acc;
        } else {
            val = Wv[kk * HD + (n - 2 * HD)];
        }
        WcatT[t] = f2bf(val);
    } else if (t < WCOLS * CIN + COUT * HD) {  // WoutT: u = n*128 + kk
        int u = t - WCOLS * CIN;
        int n = u >> 7, kk = u & 127;
        WoutT[u] = f2bf(Wout[kk * COUT + n]);
    } else if (t < WCOLS * CIN + COUT * HD + 3 * HD) {
        int u = t - (WCOLS * CIN + COUT * HD);
        int r = u / HD, j = u % HD;
        const float* w = P2 + r * HD;
        float acc = 0.f;
        #pragma unroll 4
        for (int m = 0; m < HD; m += 4) {
            float4 wr = *(const float4*)(w + m);
            acc += wr.x * A1[(m+0)*HD + j] + wr.y * A1[(m+1)*HD + j]
                 + wr.z * A1[(m+2)*HD + j] + wr.w * A1[(m+3)*HD + j];
        }
        P2A1[u] = acc;
    } else if (t < WCOLS * CIN + COUT * HD + 3 * HD + HD) {
        int j = t - (WCOLS * CIN + COUT * HD + 3 * HD);
        float acc = b1[j];
        #pragma unroll 4
        for (int m = 0; m < HD; m += 4) {
            float4 wr = *(const float4*)(bp2 + m);
            acc += wr.x * A1[(m+0)*HD + j] + wr.y * A1[(m+1)*HD + j]
                 + wr.z * A1[(m+2)*HD + j] + wr.w * A1[(m+3)*HD + j];
        }
        cvec[j] = acc;
    }
}

// ---------------------------------------------------------------------------
// Kernel A (MFMA): QKVb[16384][384] bf16 = bf16(F) @ Wcat (+cvec on n<128).
// n<128: pre-ReLU z query part; 128..255: K; 256..383: V.
// Block: 64 rows, 4 waves (wave = 16 rows), K=64 (2 mfma/nt), nt=24.
// ---------------------------------------------------------------------------
#define AK 88
__global__ __launch_bounds__(256) void qkv_kernel(const float* __restrict__ F,
                                                  const unsigned short* __restrict__ WcatT,
                                                  const float* __restrict__ cvec,
                                                  unsigned short* __restrict__ QKVb) {
    __shared__ unsigned short Af[64 * AK];     // 11.3 KB
    __shared__ unsigned short Bf[WCOLS * AK];  // 67.6 KB
    int p0 = blockIdx.x * 64;
    int t = threadIdx.x;

    // stage A: 64x64 fp32 -> bf16
    #pragma unroll
    for (int i = 0; i < 4; ++i) {
        int v = t + i * 256;
        int row = v >> 4, c4 = (v & 15) * 4;
        float4 fa = *(const float4*)(F + (p0 + row) * CIN + c4);
        uint2 u = make_uint2(pack2(fa.x, fa.y), pack2(fa.z, fa.w));
        *(uint2*)(&Af[row * AK + c4]) = u;
    }
    // stage B: 384x64 bf16
    #pragma unroll
    for (int i = 0; i < 12; ++i) {
        int v = t + i * 256;                   // uint4 index: n = v>>3, j16 = v&7
        int n = v >> 3, j16 = v & 7;
        *(uint4*)(&Bf[n * AK + j16 * 8]) = ((const uint4*)WcatT)[v];
    }
    __syncthreads();

    int w = t >> 6, l = t & 63;
    int ml = l & 15, quad = l >> 4;
    int m0 = w * 16;

    short8 a0 = *(const short8*)(&Af[(m0 + ml) * AK + quad * 8]);
    short8 a1 = *(const short8*)(&Af[(m0 + ml) * AK + 32 + quad * 8]);

    #pragma unroll
    for (int nt = 0; nt < 24; ++nt) {
        short8 b0 = *(const short8*)(&Bf[(nt * 16 + ml) * AK + quad * 8]);
        short8 b1 = *(const short8*)(&Bf[(nt * 16 + ml) * AK + 32 + quad * 8]);
        float4v acc = {0.f, 0.f, 0.f, 0.f};
        acc = __builtin_amdgcn_mfma_f32_16x16x32_bf16(a0, b0, acc, 0, 0, 0);
        acc = __builtin_amdgcn_mfma_f32_16x16x32_bf16(a1, b1, acc, 0, 0, 0);
        int n = nt * 16 + ml;
        float cadd = (n < HD) ? cvec[n] : 0.f;
        #pragma unroll
        for (int r = 0; r < 4; ++r) {
            int row = p0 + m0 + quad * 4 + r;
            QKVb[row * WCOLS + n] = f2bf(acc[r] + cadd);
        }
    }
}

// ---------------------------------------------------------------------------
// Kernel B (REWRITTEN): wave-per-point attention. 4 points/block, 0 per-phase
// barriers (1 block-start barrier for LDS table staging only).
// lane = k(0..15) x cg(0..3); cg's 32 channels == head cg.
//  - logits: per-lane partial over 32 ch -> shfl_xor(16,32) over cg
//  - softmax over K=16: DPP row ops (row = 16 lanes = the 16 neighbors)
//  - V-reduce + pe-reduce: DPP row sums
// ---------------------------------------------------------------------------
__global__ __launch_bounds__(256) void attn_kernel(
        const float* __restrict__ xyzs, const int* __restrict__ kg,
        const unsigned short* __restrict__ QKVb,
        const float* __restrict__ P1, const float* __restrict__ bp1,
        const float* __restrict__ P2, const float* __restrict__ bp2,
        const float* __restrict__ P2A1,
        const float* __restrict__ A2, const float* __restrict__ b2,
        unsigned short* __restrict__ FUSEDb) {
    __shared__ float4 A2s[HD];   // A2[ch][0..3]
    __shared__ float4 WAs[HD];   // (P2A1[0][ch], P2A1[1][ch], P2A1[2][ch], -)
    __shared__ float4 P2s[HD];   // (P2[0][ch], P2[1][ch], P2[2][ch], bp2[ch])
    int t = threadIdx.x;
    if (t < HD) {
        A2s[t] = *(const float4*)(A2 + t * 4);
        WAs[t] = make_float4(P2A1[t], P2A1[HD + t], P2A1[2 * HD + t], 0.f);
        P2s[t] = make_float4(P2[t], P2[HD + t], P2[2 * HD + t], bp2[t]);
    }
    __syncthreads();   // once per block; no further barriers

    int lane = t & 63;
    int p = blockIdx.x * 4 + (t >> 6);
    int b = p >> 13;                 // p / NPTS
    int k = lane & 15, cg = lane >> 4;
    int c0 = cg * 32;

    int idx = kg[p * KNN + k];
    int q = b * NPTS + idx;

    float r0 = xyzs[p * 3 + 0] - xyzs[q * 3 + 0];
    float r1 = xyzs[p * 3 + 1] - xyzs[q * 3 + 1];
    float r2 = xyzs[p * 3 + 2] - xyzs[q * 3 + 2];
    float h0 = fmaxf(r0 * P1[0] + r1 * P1[3] + r2 * P1[6] + bp1[0], 0.f);
    float h1 = fmaxf(r0 * P1[1] + r1 * P1[4] + r2 * P1[7] + bp1[1], 0.f);
    float h2 = fmaxf(r0 * P1[2] + r1 * P1[5] + r2 * P1[8] + bp1[2], 0.f);

    const uint4* qp = (const uint4*)(QKVb + (size_t)p * WCOLS + c0);
    const uint4* kp = (const uint4*)(QKVb + (size_t)q * WCOLS + HD + c0);
    const uint4* vp = (const uint4*)(QKVb + (size_t)q * WCOLS + 2 * HD + c0);
    uint4 quA[4] = {qp[0], qp[1], qp[2], qp[3]};
    uint4 kuA[4] = {kp[0], kp[1], kp[2], kp[3]};
    uint4 vuA[4] = {vp[0], vp[1], vp[2], vp[3]};

    // logit partials over this lane's 32 channels, all 4 heads
    float pl0 = 0.f, pl1 = 0.f, pl2 = 0.f, pl3 = 0.f;
    #pragma unroll
    for (int jc = 0; jc < 4; ++jc) {
        float qz[8], kr[8];
        unpack8(quA[jc], qz);
        unpack8(kuA[jc], kr);
        #pragma unroll
        for (int jj = 0; jj < 8; ++jj) {
            int ch = c0 + jc * 8 + jj;
            float4 wa = WAs[ch];    // 16-lane broadcast read
            float z = fmaxf(qz[jj] - kr[jj] + h0 * wa.x + h1 * wa.y + h2 * wa.z, 0.f);
            float4 ar = A2s[ch];
            pl0 += z * ar.x; pl1 += z * ar.y; pl2 += z * ar.z; pl3 += z * ar.w;
        }
    }
    // reduce over the 4 channel groups (lanes differing in bits 4,5)
    pl0 += __shfl_xor(pl0, 16, 64); pl0 += __shfl_xor(pl0, 32, 64);
    pl1 += __shfl_xor(pl1, 16, 64); pl1 += __shfl_xor(pl1, 32, 64);
    pl2 += __shfl_xor(pl2, 16, 64); pl2 += __shfl_xor(pl2, 32, 64);
    pl3 += __shfl_xor(pl3, 16, 64); pl3 += __shfl_xor(pl3, 32, 64);

    // this lane's head is cg; b2 is constant over K -> cancels in softmax
    float lgt = pl0;
    lgt = (cg == 1) ? pl1 : lgt;
    lgt = (cg == 2) ? pl2 : lgt;
    lgt = (cg == 3) ? pl3 : lgt;

    // softmax over K=16 within the 16-lane row
    float m = ror_max16(lgt);
    float e = __expf(lgt - m);
    float s = ror_sum16(e);
    float a = e / s;

    // pe weighted sums for head cg (pe = h @ P2 + bp2; sum_k a = 1)
    float hb0 = ror_sum16(a * h0);
    float hb1 = ror_sum16(a * h1);
    float hb2 = ror_sum16(a * h2);

    // V weighted sum + epilogue; chunk jc written by lane k==jc of each row
    #pragma unroll
    for (int jc = 0; jc < 4; ++jc) {
        float vr[8];
        unpack8(vuA[jc], vr);
        float wv[8];
        #pragma unroll
        for (int jj = 0; jj < 8; ++jj) wv[jj] = ror_sum16(a * vr[jj]);
        if (k == jc) {
            float f[8];
            #pragma unroll
            for (int jj = 0; jj < 8; ++jj) {
                float4 pp = P2s[c0 + jc * 8 + jj];
                f[jj] = wv[jj] + hb0 * pp.x + hb1 * pp.y + hb2 * pp.z + pp.w;
            }
            uint4 fu;
            fu.x = pack2(f[0], f[1]); fu.y = pack2(f[2], f[3]);
            fu.z = pack2(f[4], f[5]); fu.w = pack2(f[6], f[7]);
            *(uint4*)(FUSEDb + (size_t)p * HD + c0 + jc * 8) = fu;
        }
    }
}

// ---------------------------------------------------------------------------
// Kernel C (MFMA): out[16384][128] = FUSEDb @ Wout + bout (fp32 out).
// ---------------------------------------------------------------------------
#define OK2 144
__global__ __launch_bounds__(256) void out_kernel(const unsigned short* __restrict__ FUSEDb,
                                                  const unsigned short* __restrict__ WoutT,
                                                  const float* __restrict__ bout,
                                                  float* __restrict__ out) {
    __shared__ unsigned short Af[64 * OK2];    // 18.4 KB
    __shared__ unsigned short Bf[HD * OK2];    // 36.9 KB
    int p0 = blockIdx.x * 64;
    int t = threadIdx.x;

    #pragma unroll
    for (int i = 0; i < 4; ++i) {              // stage A: 64 x 128 bf16
        int v = t + i * 256;
        int row = v >> 4, j16 = v & 15;
        *(uint4*)(&Af[row * OK2 + j16 * 8]) = ((const uint4*)FUSEDb)[(p0 + row) * 16 + j16];
    }
    #pragma unroll
    for (int i = 0; i < 8; ++i) {              // stage B: 128 x 128 bf16
        int v = t + i * 256;
        int n = v >> 4, j16 = v & 15;
        *(uint4*)(&Bf[n * OK2 + j16 * 8]) = ((const uint4*)WoutT)[v];
    }
    __syncthreads();

    int w = t >> 6, l = t & 63;
    int ml = l & 15, quad = l >> 4;
    int m0 = w * 16;

    short8 af[4];
    #pragma unroll
    for (int ks = 0; ks < 4; ++ks)
        af[ks] = *(const short8*)(&Af[(m0 + ml) * OK2 + ks * 32 + quad * 8]);

    #pragma unroll
    for (int nt = 0; nt < 8; ++nt) {
        float4v acc = {0.f, 0.f, 0.f, 0.f};
        #pragma unroll
        for (int ks = 0; ks < 4; ++ks) {
            short8 bf = *(const short8*)(&Bf[(nt * 16 + ml) * OK2 + ks * 32 + quad * 8]);
            acc = __builtin_amdgcn_mfma_f32_16x16x32_bf16(af[ks], bf, acc, 0, 0, 0);
        }
        int n = nt * 16 + ml;
        float bo = bout[n];
        #pragma unroll
        for (int r = 0; r < 4; ++r) {
            int row = p0 + m0 + quad * 4 + r;
            out[row * COUT + n] = acc[r] + bo;
        }
    }
}

// ---------------------------------------------------------------------------
extern "C" void kernel_launch(void* const* d_in, const int* in_sizes, int n_in,
                              void* d_out, int out_size, void* d_ws, size_t ws_size,
                              hipStream_t stream) {
    const float* xyzs = (const float*)d_in[0];
    const float* feat = (const float*)d_in[1];
    const int*   kg   = (const int*)  d_in[2];
    const float* Wk   = (const float*)d_in[3];
    const float* Wv   = (const float*)d_in[4];
    const float* Wq   = (const float*)d_in[5];
    const float* A1   = (const float*)d_in[6];
    const float* b1   = (const float*)d_in[7];
    const float* A2   = (const float*)d_in[8];
    const float* b2   = (const float*)d_in[9];
    const float* P1   = (const float*)d_in[10];
    const float* bp1  = (const float*)d_in[11];
    const float* P2   = (const float*)d_in[12];
    const float* bp2  = (const float*)d_in[13];
    const float* Wout = (const float*)d_in[14];
    const float* bout = (const float*)d_in[15];
    float* out = (float*)d_out;

    float* ws = (float*)d_ws;
    float* cvec = ws;                               // 128 fp32
    float* P2A1 = ws + 128;                         // 384 fp32  (total 512 fp32 = 2048 B)
    unsigned short* QKVb  = (unsigned short*)(ws + 512);         // BN*384 bf16 (12.6 MB)
    unsigned short* FUSEDb = QKVb + (size_t)BN * WCOLS;          // BN*128 bf16 (4 MB)
    unsigned short* WcatT = FUSEDb + (size_t)BN * HD;            // 384*64 bf16
    unsigned short* WoutT = WcatT + WCOLS * CIN;                 // 128*128 bf16

    int prep_elems = WCOLS*CIN + COUT*HD + 3*HD + HD;  // 41472
    prep_kernel<<<(prep_elems + 255) / 256, 256, 0, stream>>>(
        Wk, Wv, Wq, A1, b1, P2, bp2, Wout, WcatT, WoutT, P2A1, cvec);

    qkv_kernel<<<BN / 64, 256, 0, stream>>>(feat, WcatT, cvec, QKVb);

    attn_kernel<<<BN / 4, 256, 0, stream>>>(
        xyzs, kg, QKVb, P1, bp1, P2, bp2, P2A1, A2, b2, FUSEDb);

    out_kernel<<<BN / 64, 256, 0, stream>>>(FUSEDb, WoutT, bout, out);
}

// Round 3
// 132.631 us; speedup vs baseline: 1.1945x; 1.0573x over previous
//
#include <hip/hip_runtime.h>
#include <hip/hip_bf16.h>

// Problem constants (fixed by reference)
#define BATCH 2
#define NPTS  8192
#define BN    (BATCH * NPTS)   // 16384
#define KNN   16
#define HEADS 4
#define HD    128              // HEADS*32
#define CIN   64
#define COUT  128
#define WCOLS 384              // [WqA1 | WkA1 | Wv] columns

using short8  = __attribute__((ext_vector_type(8))) short;
using float4v = __attribute__((ext_vector_type(4))) float;
using float2v = __attribute__((ext_vector_type(2))) float;

static __device__ __forceinline__ unsigned short f2bf(float x) {
    unsigned u = __float_as_uint(x);
    u += 0x7fffu + ((u >> 16) & 1u);          // round-to-nearest-even
    return (unsigned short)(u >> 16);
}
static __device__ __forceinline__ float bf_lo(unsigned u) { return __uint_as_float(u << 16); }
static __device__ __forceinline__ float bf_hi(unsigned u) { return __uint_as_float(u & 0xffff0000u); }
static __device__ __forceinline__ unsigned pack2(float a, float b) {
    return (unsigned)f2bf(a) | ((unsigned)f2bf(b) << 16);
}
// one packed uint (2 adjacent bf16 channels) -> float2v {even, odd}
static __device__ __forceinline__ float2v bf2pair(unsigned u) {
    float2v r;
    r.x = __uint_as_float(u << 16);
    r.y = __uint_as_float(u & 0xffff0000u);
    return r;
}

// ---- packed fp32 VOP3P (v_pk_*_f32): 2 f32 per instruction ----
static __device__ __forceinline__ float2v pk_add(float2v a, float2v b) {
    float2v d;
    asm("v_pk_add_f32 %0, %1, %2" : "=v"(d) : "v"(a), "v"(b));
    return d;
}
static __device__ __forceinline__ float2v pk_sub(float2v a, float2v b) {
    float2v d;
    asm("v_pk_add_f32 %0, %1, %2 neg_lo:[0,1] neg_hi:[0,1]" : "=v"(d) : "v"(a), "v"(b));
    return d;
}
static __device__ __forceinline__ float2v pk_mul(float2v a, float2v b) {
    float2v d;
    asm("v_pk_mul_f32 %0, %1, %2" : "=v"(d) : "v"(a), "v"(b));
    return d;
}
static __device__ __forceinline__ float2v pk_fma(float2v a, float2v b, float2v c) {
    float2v d;
    asm("v_pk_fma_f32 %0, %1, %2, %3" : "=v"(d) : "v"(a), "v"(b), "v"(c));
    return d;
}
static __device__ __forceinline__ float2v sx2(float2v v, int mask) {
    float2v r;
    r.x = __shfl_xor(v.x, mask, 64);
    r.y = __shfl_xor(v.y, mask, 64);
    return r;
}

// DPP row ops (row = 16 lanes). row_ror:n ctrl = 0x120+n.
template <int CTRL>
static __device__ __forceinline__ float dpp_mov(float x) {
    return __int_as_float(
        __builtin_amdgcn_update_dpp(0, __float_as_int(x), CTRL, 0xf, 0xf, false));
}
static __device__ __forceinline__ float ror_sum16(float x) {
    x += dpp_mov<0x128>(x);
    x += dpp_mov<0x124>(x);
    x += dpp_mov<0x122>(x);
    x += dpp_mov<0x121>(x);
    return x;
}
static __device__ __forceinline__ float ror_max16(float x) {
    x = fmaxf(x, dpp_mov<0x128>(x));
    x = fmaxf(x, dpp_mov<0x124>(x));
    x = fmaxf(x, dpp_mov<0x122>(x));
    x = fmaxf(x, dpp_mov<0x121>(x));
    return x;
}

// ---------------------------------------------------------------------------
// Kernel P: fold weights into MFMA-ready transposed bf16 operands.
// ---------------------------------------------------------------------------
__global__ void prep_kernel(const float* __restrict__ Wk,
                            const float* __restrict__ Wv,
                            const float* __restrict__ Wq,
                            const float* __restrict__ A1,
                            const float* __restrict__ b1,
                            const float* __restrict__ P2,
                            const float* __restrict__ bp2,
                            const float* __restrict__ Wout,
                            unsigned short* __restrict__ WcatT,
                            unsigned short* __restrict__ WoutT,
                            float* __restrict__ P2A1,
                            float* __restrict__ cvec) {
    int t = blockIdx.x * blockDim.x + threadIdx.x;
    if (t < WCOLS * CIN) {                     // WcatT: u = n*64 + kk
        int n = t >> 6, kk = t & 63;
        float val;
        if (n < 2 * HD) {
            const float* w = (n < HD ? Wq : Wk) + kk * HD;
            int jj = n & (HD - 1);
            float acc = 0.f;
            #pragma unroll 4
            for (int m = 0; m < HD; m += 4) {
                float4 wr = *(const float4*)(w + m);
                acc += wr.x * A1[(m+0)*HD + jj] + wr.y * A1[(m+1)*HD + jj]
                     + wr.z * A1[(m+2)*HD + jj] + wr.w * A1[(m+3)*HD + jj];
            }
            val = acc;
        } else {
            val = Wv[kk * HD + (n - 2 * HD)];
        }
        WcatT[t] = f2bf(val);
    } else if (t < WCOLS * CIN + COUT * HD) {  // WoutT: u = n*128 + kk
        int u = t - WCOLS * CIN;
        int n = u >> 7, kk = u & 127;
        WoutT[u] = f2bf(Wout[kk * COUT + n]);
    } else if (t < WCOLS * CIN + COUT * HD + 3 * HD) {
        int u = t - (WCOLS * CIN + COUT * HD);
        int r = u / HD, j = u % HD;
        const float* w = P2 + r * HD;
        float acc = 0.f;
        #pragma unroll 4
        for (int m = 0; m < HD; m += 4) {
            float4 wr = *(const float4*)(w + m);
            acc += wr.x * A1[(m+0)*HD + j] + wr.y * A1[(m+1)*HD + j]
                 + wr.z * A1[(m+2)*HD + j] + wr.w * A1[(m+3)*HD + j];
        }
        P2A1[u] = acc;
    } else if (t < WCOLS * CIN + COUT * HD + 3 * HD + HD) {
        int j = t - (WCOLS * CIN + COUT * HD + 3 * HD);
        float acc = b1[j];
        #pragma unroll 4
        for (int m = 0; m < HD; m += 4) {
            float4 wr = *(const float4*)(bp2 + m);
            acc += wr.x * A1[(m+0)*HD + j] + wr.y * A1[(m+1)*HD + j]
                 + wr.z * A1[(m+2)*HD + j] + wr.w * A1[(m+3)*HD + j];
        }
        cvec[j] = acc;
    }
}

// ---------------------------------------------------------------------------
// Kernel A (MFMA): QKVb[16384][384] bf16 = bf16(F) @ Wcat (+cvec on n<128).
// ---------------------------------------------------------------------------
#define AK 88
__global__ __launch_bounds__(256) void qkv_kernel(const float* __restrict__ F,
                                                  const unsigned short* __restrict__ WcatT,
                                                  const float* __restrict__ cvec,
                                                  unsigned short* __restrict__ QKVb) {
    __shared__ unsigned short Af[64 * AK];     // 11.3 KB
    __shared__ unsigned short Bf[WCOLS * AK];  // 67.6 KB
    int p0 = blockIdx.x * 64;
    int t = threadIdx.x;

    // stage A: 64x64 fp32 -> bf16
    #pragma unroll
    for (int i = 0; i < 4; ++i) {
        int v = t + i * 256;
        int row = v >> 4, c4 = (v & 15) * 4;
        float4 fa = *(const float4*)(F + (p0 + row) * CIN + c4);
        uint2 u = make_uint2(pack2(fa.x, fa.y), pack2(fa.z, fa.w));
        *(uint2*)(&Af[row * AK + c4]) = u;
    }
    // stage B: 384x64 bf16
    #pragma unroll
    for (int i = 0; i < 12; ++i) {
        int v = t + i * 256;                   // uint4 index: n = v>>3, j16 = v&7
        int n = v >> 3, j16 = v & 7;
        *(uint4*)(&Bf[n * AK + j16 * 8]) = ((const uint4*)WcatT)[v];
    }
    __syncthreads();

    int w = t >> 6, l = t & 63;
    int ml = l & 15, quad = l >> 4;
    int m0 = w * 16;

    short8 a0 = *(const short8*)(&Af[(m0 + ml) * AK + quad * 8]);
    short8 a1 = *(const short8*)(&Af[(m0 + ml) * AK + 32 + quad * 8]);

    #pragma unroll
    for (int nt = 0; nt < 24; ++nt) {
        short8 b0 = *(const short8*)(&Bf[(nt * 16 + ml) * AK + quad * 8]);
        short8 b1 = *(const short8*)(&Bf[(nt * 16 + ml) * AK + 32 + quad * 8]);
        float4v acc = {0.f, 0.f, 0.f, 0.f};
        acc = __builtin_amdgcn_mfma_f32_16x16x32_bf16(a0, b0, acc, 0, 0, 0);
        acc = __builtin_amdgcn_mfma_f32_16x16x32_bf16(a1, b1, acc, 0, 0, 0);
        int n = nt * 16 + ml;
        float cadd = (n < HD) ? cvec[n] : 0.f;
        #pragma unroll
        for (int r = 0; r < 4; ++r) {
            int row = p0 + m0 + quad * 4 + r;
            QKVb[row * WCOLS + n] = f2bf(acc[r] + cadd);
        }
    }
}

// ---------------------------------------------------------------------------
// Kernel B: wave-per-point attention, v_pk_f32 packed math + reduce-scatter V.
// lane = k(0..15) x cg(0..3); cg's 32 channels == head cg.
//  - z/logit loop: channel pairs via v_pk_fma_f32 (2 f32/instr)
//  - logits: shfl_xor(16,32) over cg
//  - softmax over K=16: DPP row ops
//  - V-reduce: 4-stage shfl_xor butterfly reduce-scatter; lane k ends with
//    chunk (k>>2)&3 fully summed; lanes k%4==0 write.
// ---------------------------------------------------------------------------
__global__ __launch_bounds__(256) void attn_kernel(
        const float* __restrict__ xyzs, const int* __restrict__ kg,
        const unsigned short* __restrict__ QKVb,
        const float* __restrict__ P1, const float* __restrict__ bp1,
        const float* __restrict__ P2, const float* __restrict__ bp2,
        const float* __restrict__ P2A1,
        const float* __restrict__ A2, const float* __restrict__ b2,
        unsigned short* __restrict__ FUSEDb) {
    // channel-pair-major tables (pair pi = channels 2pi, 2pi+1)
    __shared__ float4 A2pA[64];   // {A2[2c][0],A2[2c+1][0],A2[2c][1],A2[2c+1][1]}
    __shared__ float4 A2pB[64];   // heads 2,3
    __shared__ float4 WApA[64];   // {P2A1[0][2c],P2A1[0][2c+1],P2A1[1][2c],P2A1[1][2c+1]}
    __shared__ float2 WApB[64];   // {P2A1[2][2c],P2A1[2][2c+1]}
    __shared__ float4 P2s[HD];    // (P2[0][ch], P2[1][ch], P2[2][ch], bp2[ch])
    int t = threadIdx.x;
    if (t < 64) {
        int c = t * 2;
        float4 a2l = *(const float4*)(A2 + c * 4);
        float4 a2h = *(const float4*)(A2 + (c + 1) * 4);
        A2pA[t] = make_float4(a2l.x, a2h.x, a2l.y, a2h.y);
        A2pB[t] = make_float4(a2l.z, a2h.z, a2l.w, a2h.w);
        WApA[t] = make_float4(P2A1[c], P2A1[c + 1], P2A1[HD + c], P2A1[HD + c + 1]);
        WApB[t] = make_float2(P2A1[2 * HD + c], P2A1[2 * HD + c + 1]);
    }
    if (t < HD) P2s[t] = make_float4(P2[t], P2[HD + t], P2[2 * HD + t], bp2[t]);
    __syncthreads();   // once per block; no further barriers

    int lane = t & 63;
    int p = blockIdx.x * 4 + (t >> 6);
    int b = p >> 13;                 // p / NPTS
    int k = lane & 15, cg = lane >> 4;
    int c0 = cg * 32;

    int idx = kg[p * KNN + k];
    int q = b * NPTS + idx;

    float r0 = xyzs[p * 3 + 0] - xyzs[q * 3 + 0];
    float r1 = xyzs[p * 3 + 1] - xyzs[q * 3 + 1];
    float r2 = xyzs[p * 3 + 2] - xyzs[q * 3 + 2];
    float h0 = fmaxf(r0 * P1[0] + r1 * P1[3] + r2 * P1[6] + bp1[0], 0.f);
    float h1 = fmaxf(r0 * P1[1] + r1 * P1[4] + r2 * P1[7] + bp1[1], 0.f);
    float h2 = fmaxf(r0 * P1[2] + r1 * P1[5] + r2 * P1[8] + bp1[2], 0.f);

    const uint4* qp = (const uint4*)(QKVb + (size_t)p * WCOLS + c0);
    const uint4* kp = (const uint4*)(QKVb + (size_t)q * WCOLS + HD + c0);
    const uint4* vp = (const uint4*)(QKVb + (size_t)q * WCOLS + 2 * HD + c0);
    uint4 quA[4] = {qp[0], qp[1], qp[2], qp[3]};
    uint4 kuA[4] = {kp[0], kp[1], kp[2], kp[3]};
    uint4 vuA[4] = {vp[0], vp[1], vp[2], vp[3]};

    float2v h0p = {h0, h0}, h1p = {h1, h1}, h2p = {h2, h2};
    float2v pl0 = {0.f, 0.f}, pl1 = {0.f, 0.f}, pl2 = {0.f, 0.f}, pl3 = {0.f, 0.f};
    int pbase = cg * 16;   // pair index base (c0/2)

    #pragma unroll
    for (int jc = 0; jc < 4; ++jc) {
        const unsigned* uq = (const unsigned*)&quA[jc];
        const unsigned* uk = (const unsigned*)&kuA[jc];
        #pragma unroll
        for (int jp = 0; jp < 4; ++jp) {     // pair = channels (2jp, 2jp+1) of chunk
            float2v qp2 = bf2pair(uq[jp]);
            float2v kp2 = bf2pair(uk[jp]);
            int pi = pbase + jc * 4 + jp;
            float4 wa = WApA[pi];
            float2 wb = WApB[pi];
            float2v acc = pk_sub(qp2, kp2);
            acc = pk_fma(h0p, (float2v){wa.x, wa.y}, acc);
            acc = pk_fma(h1p, (float2v){wa.z, wa.w}, acc);
            acc = pk_fma(h2p, (float2v){wb.x, wb.y}, acc);
            float2v z2;
            z2.x = fmaxf(acc.x, 0.f);
            z2.y = fmaxf(acc.y, 0.f);
            float4 aA = A2pA[pi], aB = A2pB[pi];
            pl0 = pk_fma(z2, (float2v){aA.x, aA.y}, pl0);
            pl1 = pk_fma(z2, (float2v){aA.z, aA.w}, pl1);
            pl2 = pk_fma(z2, (float2v){aB.x, aB.y}, pl2);
            pl3 = pk_fma(z2, (float2v){aB.z, aB.w}, pl3);
        }
    }
    float l0 = pl0.x + pl0.y;
    float l1 = pl1.x + pl1.y;
    float l2 = pl2.x + pl2.y;
    float l3 = pl3.x + pl3.y;

    // reduce over the 4 channel groups (lanes differing in bits 4,5)
    l0 += __shfl_xor(l0, 16, 64); l0 += __shfl_xor(l0, 32, 64);
    l1 += __shfl_xor(l1, 16, 64); l1 += __shfl_xor(l1, 32, 64);
    l2 += __shfl_xor(l2, 16, 64); l2 += __shfl_xor(l2, 32, 64);
    l3 += __shfl_xor(l3, 16, 64); l3 += __shfl_xor(l3, 32, 64);

    // this lane's head is cg; b2 is constant over K -> cancels in softmax
    float lgt = l0;
    lgt = (cg == 1) ? l1 : lgt;
    lgt = (cg == 2) ? l2 : lgt;
    lgt = (cg == 3) ? l3 : lgt;

    // softmax over K=16 within the 16-lane row
    float m16 = ror_max16(lgt);
    float e = __expf(lgt - m16);
    float s = ror_sum16(e);
    float a = e / s;

    // pe weighted sums for head cg (pe = h @ P2 + bp2; sum_k a = 1)
    float hb0 = ror_sum16(a * h0);
    float hb1 = ror_sum16(a * h1);
    float hb2 = ror_sum16(a * h2);

    // ---- V weighted sum: butterfly reduce-scatter over the 16-lane row ----
    float2v ap = {a, a};
    float2v y0[4], y1[4], y2[4], y3[4];
    {
        const unsigned* v0 = (const unsigned*)&vuA[0];
        const unsigned* v1 = (const unsigned*)&vuA[1];
        const unsigned* v2 = (const unsigned*)&vuA[2];
        const unsigned* v3 = (const unsigned*)&vuA[3];
        #pragma unroll
        for (int i = 0; i < 4; ++i) {
            y0[i] = pk_mul(ap, bf2pair(v0[i]));
            y1[i] = pk_mul(ap, bf2pair(v1[i]));
            y2[i] = pk_mul(ap, bf2pair(v2[i]));
            y3[i] = pk_mul(ap, bf2pair(v3[i]));
        }
    }
    bool hi3 = (k & 8) != 0;
    float2v k0[4], k1[4];
    #pragma unroll
    for (int i = 0; i < 4; ++i) {
        float2v s0 = hi3 ? y0[i] : y2[i];      // what my partner keeps
        float2v s1 = hi3 ? y1[i] : y3[i];
        float2v r0v = sx2(s0, 8);
        float2v r1v = sx2(s1, 8);
        k0[i] = pk_add(hi3 ? y2[i] : y0[i], r0v);   // my kept chunks
        k1[i] = pk_add(hi3 ? y3[i] : y1[i], r1v);
    }
    bool hi2 = (k & 4) != 0;
    float2v m2[4];
    #pragma unroll
    for (int i = 0; i < 4; ++i) {
        float2v sv = hi2 ? k0[i] : k1[i];
        float2v rv = sx2(sv, 4);
        m2[i] = pk_add(hi2 ? k1[i] : k0[i], rv);
    }
    #pragma unroll
    for (int i = 0; i < 4; ++i) m2[i] = pk_add(m2[i], sx2(m2[i], 2));
    #pragma unroll
    for (int i = 0; i < 4; ++i) m2[i] = pk_add(m2[i], sx2(m2[i], 1));
    // lane k now holds chunk (k>>2)&3 fully summed over the row

    if ((k & 3) == 0) {
        int jc = k >> 2;
        float f[8];
        #pragma unroll
        for (int i = 0; i < 4; ++i) {
            float4 pp0 = P2s[c0 + jc * 8 + 2 * i];
            float4 pp1 = P2s[c0 + jc * 8 + 2 * i + 1];
            f[2 * i]     = m2[i].x + hb0 * pp0.x + hb1 * pp0.y + hb2 * pp0.z + pp0.w;
            f[2 * i + 1] = m2[i].y + hb0 * pp1.x + hb1 * pp1.y + hb2 * pp1.z + pp1.w;
        }
        uint4 fu;
        fu.x = pack2(f[0], f[1]); fu.y = pack2(f[2], f[3]);
        fu.z = pack2(f[4], f[5]); fu.w = pack2(f[6], f[7]);
        *(uint4*)(FUSEDb + (size_t)p * HD + c0 + jc * 8) = fu;
    }
}

// ---------------------------------------------------------------------------
// Kernel C (MFMA): out[16384][128] = FUSEDb @ Wout + bout (fp32 out).
// ---------------------------------------------------------------------------
#define OK2 144
__global__ __launch_bounds__(256) void out_kernel(const unsigned short* __restrict__ FUSEDb,
                                                  const unsigned short* __restrict__ WoutT,
                                                  const float* __restrict__ bout,
                                                  float* __restrict__ out) {
    __shared__ unsigned short Af[64 * OK2];    // 18.4 KB
    __shared__ unsigned short Bf[HD * OK2];    // 36.9 KB
    int p0 = blockIdx.x * 64;
    int t = threadIdx.x;

    #pragma unroll
    for (int i = 0; i < 4; ++i) {              // stage A: 64 x 128 bf16
        int v = t + i * 256;
        int row = v >> 4, j16 = v & 15;
        *(uint4*)(&Af[row * OK2 + j16 * 8]) = ((const uint4*)FUSEDb)[(p0 + row) * 16 + j16];
    }
    #pragma unroll
    for (int i = 0; i < 8; ++i) {              // stage B: 128 x 128 bf16
        int v = t + i * 256;
        int n = v >> 4, j16 = v & 15;
        *(uint4*)(&Bf[n * OK2 + j16 * 8]) = ((const uint4*)WoutT)[v];
    }
    __syncthreads();

    int w = t >> 6, l = t & 63;
    int ml = l & 15, quad = l >> 4;
    int m0 = w * 16;

    short8 af[4];
    #pragma unroll
    for (int ks = 0; ks < 4; ++ks)
        af[ks] = *(const short8*)(&Af[(m0 + ml) * OK2 + ks * 32 + quad * 8]);

    #pragma unroll
    for (int nt = 0; nt < 8; ++nt) {
        float4v acc = {0.f, 0.f, 0.f, 0.f};
        #pragma unroll
        for (int ks = 0; ks < 4; ++ks) {
            short8 bf = *(const short8*)(&Bf[(nt * 16 + ml) * OK2 + ks * 32 + quad * 8]);
            acc = __builtin_amdgcn_mfma_f32_16x16x32_bf16(af[ks], bf, acc, 0, 0, 0);
        }
        int n = nt * 16 + ml;
        float bo = bout[n];
        #pragma unroll
        for (int r = 0; r < 4; ++r) {
            int row = p0 + m0 + quad * 4 + r;
            out[row * COUT + n] = acc[r] + bo;
        }
    }
}

// ---------------------------------------------------------------------------
extern "C" void kernel_launch(void* const* d_in, const int* in_sizes, int n_in,
                              void* d_out, int out_size, void* d_ws, size_t ws_size,
                              hipStream_t stream) {
    const float* xyzs = (const float*)d_in[0];
    const float* feat = (const float*)d_in[1];
    const int*   kg   = (const int*)  d_in[2];
    const float* Wk   = (const float*)d_in[3];
    const float* Wv   = (const float*)d_in[4];
    const float* Wq   = (const float*)d_in[5];
    const float* A1   = (const float*)d_in[6];
    const float* b1   = (const float*)d_in[7];
    const float* A2   = (const float*)d_in[8];
    const float* b2   = (const float*)d_in[9];
    const float* P1   = (const float*)d_in[10];
    const float* bp1  = (const float*)d_in[11];
    const float* P2   = (const float*)d_in[12];
    const float* bp2  = (const float*)d_in[13];
    const float* Wout = (const float*)d_in[14];
    const float* bout = (const float*)d_in[15];
    float* out = (float*)d_out;

    float* ws = (float*)d_ws;
    float* cvec = ws;                               // 128 fp32
    float* P2A1 = ws + 128;                         // 384 fp32  (total 512 fp32 = 2048 B)
    unsigned short* QKVb  = (unsigned short*)(ws + 512);         // BN*384 bf16 (12.6 MB)
    unsigned short* FUSEDb = QKVb + (size_t)BN * WCOLS;          // BN*128 bf16 (4 MB)
    unsigned short* WcatT = FUSEDb + (size_t)BN * HD;            // 384*64 bf16
    unsigned short* WoutT = WcatT + WCOLS * CIN;                 // 128*128 bf16

    int prep_elems = WCOLS*CIN + COUT*HD + 3*HD + HD;  // 41472
    prep_kernel<<<(prep_elems + 255) / 256, 256, 0, stream>>>(
        Wk, Wv, Wq, A1, b1, P2, bp2, Wout, WcatT, WoutT, P2A1, cvec);

    qkv_kernel<<<BN / 64, 256, 0, stream>>>(feat, WcatT, cvec, QKVb);

    attn_kernel<<<BN / 4, 256, 0, stream>>>(
        xyzs, kg, QKVb, P1, bp1, P2, bp2, P2A1, A2, b2, FUSEDb);

    out_kernel<<<BN / 64, 256, 0, stream>>>(FUSEDb, WoutT, bout, out);
}